// Round 2
// baseline (772.323 us; speedup 1.0000x reference)
//
#include <hip/hip_runtime.h>
#include <hip/hip_bf16.h>
#include <math.h>

typedef __attribute__((ext_vector_type(8))) short short8;
typedef __attribute__((ext_vector_type(4))) float floatx4;

// ---------------------------------------------------------------- helpers
__device__ __forceinline__ void load_lds16(const void* g, void* l) {
  __builtin_amdgcn_global_load_lds(
      (__attribute__((address_space(1))) void*)(g),
      (__attribute__((address_space(3))) void*)(l), 16, 0, 0);
}

#define MFMA16x16x32(a, b, c) __builtin_amdgcn_mfma_f32_16x16x32_bf16((a), (b), (c), 0, 0, 0)

__device__ __forceinline__ float to_f(float x) { return x; }
__device__ __forceinline__ float to_f(__hip_bfloat16 x) { return __bfloat162float(x); }
__device__ __forceinline__ void st_val(float* p, float v) { *p = v; }
__device__ __forceinline__ void st_val(__hip_bfloat16* p, float v) { *p = __float2bfloat16(v); }

// ---------------------------------------------------------------- fp32 -> bf16 elementwise (src)
__global__ __launch_bounds__(256) void cvt_f32_bf16(const float4* __restrict__ in,
                                                    ushort* __restrict__ out) {
  int i = blockIdx.x * 256 + threadIdx.x;
  float4 v = in[i];
  ushort4 o;
  __hip_bfloat16 b0 = __float2bfloat16(v.x);
  __hip_bfloat16 b1 = __float2bfloat16(v.y);
  __hip_bfloat16 b2 = __float2bfloat16(v.z);
  __hip_bfloat16 b3 = __float2bfloat16(v.w);
  o.x = *(ushort*)&b0; o.y = *(ushort*)&b1; o.z = *(ushort*)&b2; o.w = *(ushort*)&b3;
  *(ushort4*)(out + 4 * i) = o;
}

// ---------------------------------------------------------------- fp32 weights -> bf16 transposed
__global__ void transpose_cvt(const float* __restrict__ in,
                              __hip_bfloat16* __restrict__ out, int R, int C) {
  __shared__ __hip_bfloat16 tile[32][33];
  int bx = blockIdx.x * 32, by = blockIdx.y * 32;
  int tx = threadIdx.x, ty = threadIdx.y;  // (32,8)
  for (int i = ty; i < 32; i += 8)
    tile[i][tx] = __float2bfloat16(in[(size_t)(by + i) * C + bx + tx]);
  __syncthreads();
  for (int i = ty; i < 32; i += 8) out[(size_t)(bx + i) * R + by + tx] = tile[tx][i];
}

// ---------------------------------------------------------------- GEMM: C[M,N] = A[M,K] @ BT[N,K]^T + bias, opt GELU
// 128x128 tile, BK=32, 4 waves, each wave 64x64 (4x4 MFMA 16x16x32 tiles).
// LDS layout k-slab: element (row,kk) at flat = (kk>>3)*1024 + row*8 + (kk&7)
__global__ __launch_bounds__(256) void gemm_bt(
    const __hip_bfloat16* __restrict__ A,
    const __hip_bfloat16* __restrict__ BT,
    const float* __restrict__ bias,
    __hip_bfloat16* __restrict__ C,
    int M, int N, int K, int act) {
  __shared__ __align__(16) __hip_bfloat16 As[128 * 32];
  __shared__ __align__(16) __hip_bfloat16 Bs[128 * 32];
  const int tid = threadIdx.x;
  const int wave = tid >> 6, lane = tid & 63;
  const int quad = lane >> 4, m = lane & 15;
  const int row0 = blockIdx.x * 128, col0 = blockIdx.y * 128;
  const int wm = (wave >> 1) * 64, wn = (wave & 1) * 64;
  const __hip_bfloat16* Ab = A + (size_t)row0 * K;
  const __hip_bfloat16* Bb = BT + (size_t)col0 * K;

  floatx4 acc[4][4] = {};

  for (int k0 = 0; k0 < K; k0 += 32) {
#pragma unroll
    for (int r = 0; r < 2; ++r) {
      int c = r * 4 + wave;
      int rowg = ((c & 1) * 64) + lane;
      int kg = k0 + ((c >> 1) * 8);
      load_lds16(Ab + (size_t)rowg * K + kg, &As[c * 512]);
      load_lds16(Bb + (size_t)rowg * K + kg, &Bs[c * 512]);
    }
    __syncthreads();
    short8 af[4], bfr[4];
#pragma unroll
    for (int i = 0; i < 4; ++i)
      af[i] = *(const short8*)&As[quad * 1024 + (wm + i * 16 + m) * 8];
#pragma unroll
    for (int j = 0; j < 4; ++j)
      bfr[j] = *(const short8*)&Bs[quad * 1024 + (wn + j * 16 + m) * 8];
#pragma unroll
    for (int i = 0; i < 4; ++i)
#pragma unroll
      for (int j = 0; j < 4; ++j)
        acc[i][j] = MFMA16x16x32(af[i], bfr[j], acc[i][j]);
    __syncthreads();
  }

#pragma unroll
  for (int j = 0; j < 4; ++j) {
    int col = col0 + wn + j * 16 + m;
    float bj = bias[col];
#pragma unroll
    for (int i = 0; i < 4; ++i) {
      int rowb = row0 + wm + i * 16 + quad * 4;
#pragma unroll
      for (int r = 0; r < 4; ++r) {
        float v = acc[i][j][r] + bj;
        if (act == 1) v = 0.5f * v * (1.0f + erff(v * 0.70710678118f));
        C[(size_t)(rowb + r) * N + col] = __float2bfloat16(v);
      }
    }
  }
}

// ---------------------------------------------------------------- fused attention per (b,h)
// scores = (Q K^T) * matrix * 0.125 -> fp32 out; softmax; ctx = P V (bf16 out).
__global__ __launch_bounds__(384) void attn_fused(
    const __hip_bfloat16* __restrict__ q,
    const __hip_bfloat16* __restrict__ k,
    const __hip_bfloat16* __restrict__ v,
    const float* __restrict__ mat,
    float* __restrict__ scores,
    __hip_bfloat16* __restrict__ ctx) {
  __shared__ __align__(16) __hip_bfloat16 Ks[96 * 72];   // [l_k][d], pad 64->72
  __shared__ __align__(16) __hip_bfloat16 Vt[64 * 104];  // [d][l_k], pad 96->104
  __shared__ __align__(16) __hip_bfloat16 Ps[96 * 104];  // [l_q][l_k], pad 96->104
  const int bh = blockIdx.x;
  const int b = bh >> 3, h = bh & 7;
  const __hip_bfloat16* qb = q + (size_t)b * 96 * 512 + h * 64;
  const __hip_bfloat16* kb = k + (size_t)b * 96 * 512 + h * 64;
  const __hip_bfloat16* vb = v + (size_t)b * 96 * 512 + h * 64;
  const int tid = threadIdx.x;

  // stage K [96][64] -> Ks, 16B chunks
  for (int c = tid; c < 768; c += 384) {
    int row = c >> 3, c8 = (c & 7) * 8;
    *(short8*)&Ks[row * 72 + c8] = *(const short8*)(kb + row * 512 + c8);
  }
  // stage V transposed: coalesced global read, scalar LDS writes
  {
    int d = tid & 63;
    for (int l = tid >> 6; l < 96; l += 6) Vt[d * 104 + l] = vb[l * 512 + d];
  }
  __syncthreads();

  const int wave = tid >> 6, lane = tid & 63;
  const int quad = lane >> 4, m = lane & 15;

  // phase 1: S = Q K^T (16 rows per wave, N=96, K=64)
  short8 a0 = *(const short8*)(qb + (wave * 16 + m) * 512 + quad * 8);
  short8 a1 = *(const short8*)(qb + (wave * 16 + m) * 512 + 32 + quad * 8);
  floatx4 s[6];
  const size_t mbase = ((size_t)bh * 96 + wave * 16 + quad * 4) * 96 + m;
#pragma unroll
  for (int ct = 0; ct < 6; ++ct) {
    short8 b0 = *(const short8*)&Ks[(ct * 16 + m) * 72 + quad * 8];
    short8 b1 = *(const short8*)&Ks[(ct * 16 + m) * 72 + 32 + quad * 8];
    floatx4 accv = {};
    accv = MFMA16x16x32(a0, b0, accv);
    accv = MFMA16x16x32(a1, b1, accv);
#pragma unroll
    for (int r = 0; r < 4; ++r) {
      float sv = accv[r] * 0.125f * mat[mbase + (size_t)r * 96 + ct * 16];
      accv[r] = sv;
      scores[mbase + (size_t)r * 96 + ct * 16] = sv;
    }
    s[ct] = accv;
  }

  // softmax over each row (16 lanes of a quad hold one row across 6 tiles)
#pragma unroll
  for (int r = 0; r < 4; ++r) {
    float mx = s[0][r];
#pragma unroll
    for (int ct = 1; ct < 6; ++ct) mx = fmaxf(mx, s[ct][r]);
#pragma unroll
    for (int dd = 1; dd < 16; dd <<= 1) mx = fmaxf(mx, __shfl_xor(mx, dd, 64));
    float sum = 0.f;
#pragma unroll
    for (int ct = 0; ct < 6; ++ct) {
      float e = __expf(s[ct][r] - mx);
      s[ct][r] = e;
      sum += e;
    }
#pragma unroll
    for (int dd = 1; dd < 16; dd <<= 1) sum += __shfl_xor(sum, dd, 64);
    float inv = 1.0f / sum;
#pragma unroll
    for (int ct = 0; ct < 6; ++ct)
      Ps[(wave * 16 + quad * 4 + r) * 104 + ct * 16 + m] = __float2bfloat16(s[ct][r] * inv);
  }
  __syncthreads();

  // phase 2: O = P V  (K = 96, 3 k-steps of 32)
  floatx4 o[4] = {};
#pragma unroll
  for (int ks = 0; ks < 3; ++ks) {
    short8 pa = *(const short8*)&Ps[(wave * 16 + m) * 104 + ks * 32 + quad * 8];
#pragma unroll
    for (int ct = 0; ct < 4; ++ct) {
      short8 vv = *(const short8*)&Vt[(ct * 16 + m) * 104 + ks * 32 + quad * 8];
      o[ct] = MFMA16x16x32(pa, vv, o[ct]);
    }
  }
  __hip_bfloat16* cb = ctx + (size_t)b * 96 * 512 + h * 64;
#pragma unroll
  for (int ct = 0; ct < 4; ++ct)
#pragma unroll
    for (int r = 0; r < 4; ++r)
      cb[(wave * 16 + quad * 4 + r) * 512 + ct * 16 + m] = __float2bfloat16(o[ct][r]);
}

// ---------------------------------------------------------------- residual + LayerNorm, one block per row (D=512)
template <typename RT, typename OT>
__global__ __launch_bounds__(256) void ln_res(
    const __hip_bfloat16* __restrict__ a, const RT* __restrict__ rsd,
    const float* __restrict__ g, const float* __restrict__ be,
    OT* __restrict__ out) {
  const int row = blockIdx.x;
  const int tid = threadIdx.x;
  const size_t base = (size_t)row * 512 + tid * 2;
  float x0 = __bfloat162float(a[base]) + to_f(rsd[base]);
  float x1 = __bfloat162float(a[base + 1]) + to_f(rsd[base + 1]);
  float s = x0 + x1, s2 = x0 * x0 + x1 * x1;
#pragma unroll
  for (int d = 1; d < 64; d <<= 1) {
    s += __shfl_xor(s, d, 64);
    s2 += __shfl_xor(s2, d, 64);
  }
  __shared__ float red[8];
  const int wave = tid >> 6, lane = tid & 63;
  if (lane == 0) {
    red[wave] = s;
    red[4 + wave] = s2;
  }
  __syncthreads();
  s = red[0] + red[1] + red[2] + red[3];
  s2 = red[4] + red[5] + red[6] + red[7];
  const float mean = s * (1.0f / 512.0f);
  const float var = s2 * (1.0f / 512.0f) - mean * mean;
  const float rstd = rsqrtf(var + 1e-5f);
  st_val(out + base, (x0 - mean) * rstd * g[tid * 2] + be[tid * 2]);
  st_val(out + base + 1, (x1 - mean) * rstd * g[tid * 2 + 1] + be[tid * 2 + 1]);
}

// ---------------------------------------------------------------- launch
extern "C" void kernel_launch(void* const* d_in, const int* in_sizes, int n_in,
                              void* d_out, int out_size, void* d_ws, size_t ws_size,
                              hipStream_t stream) {
  (void)in_sizes; (void)n_in; (void)out_size; (void)ws_size;
  typedef const float* cf;
  typedef __hip_bfloat16* bf;
  cf src = (cf)d_in[0];
  cf Wq = (cf)d_in[1];  cf bq = (cf)d_in[2];
  cf Wk = (cf)d_in[3];  cf bk = (cf)d_in[4];
  cf Wv = (cf)d_in[5];  cf bv = (cf)d_in[6];
  cf mat = (cf)d_in[7];
  cf Wo = (cf)d_in[8];  cf bo = (cf)d_in[9];
  cf g1 = (cf)d_in[10]; cf be1 = (cf)d_in[11];
  cf W1 = (cf)d_in[12]; cf b1 = (cf)d_in[13];
  cf W2 = (cf)d_in[14]; cf b2 = (cf)d_in[15];
  cf g2 = (cf)d_in[16]; cf be2 = (cf)d_in[17];

  char* ws = (char*)d_ws;
  const size_t SZ = (size_t)24576 * 512 * 2;  // 25,165,824 B (one bf16 activation)
  bf qb  = (bf)(ws);
  bf kb  = (bf)(ws + SZ);
  bf vb  = (bf)(ws + 2 * SZ);
  bf srcb = (bf)(ws + 3 * SZ);    // bf16 src; dead before attn writes ctx here
  bf ctx = (bf)(ws + 3 * SZ);
  bf hb  = (bf)(ws);              // FFN hidden aliases qb..ctx (dead by then)
  bf tmp = (bf)(ws + 4 * SZ);     // attn-proj out, later ffn2 out
  bf xb  = (bf)(ws + 5 * SZ);     // post-LN1 x (bf16)
  char* wt = ws + 6 * SZ;
  bf WqT = (bf)(wt);
  bf WkT = (bf)(wt + 524288);
  bf WvT = (bf)(wt + 2 * 524288);
  bf WoT = (bf)(wt + 3 * 524288);
  bf W1T = (bf)(wt + 4 * 524288);
  bf W2T = (bf)(wt + 4 * 524288 + 2097152);

  float* yout = (float*)d_out;
  float* scout = (float*)d_out + 12582912;  // scores after y

  cvt_f32_bf16<<<12288, 256, 0, stream>>>((const float4*)src, (ushort*)srcb);

  dim3 tb(32, 8);
  transpose_cvt<<<dim3(16, 16), tb, 0, stream>>>(Wq, WqT, 512, 512);
  transpose_cvt<<<dim3(16, 16), tb, 0, stream>>>(Wk, WkT, 512, 512);
  transpose_cvt<<<dim3(16, 16), tb, 0, stream>>>(Wv, WvT, 512, 512);
  transpose_cvt<<<dim3(16, 16), tb, 0, stream>>>(Wo, WoT, 512, 512);
  transpose_cvt<<<dim3(64, 16), tb, 0, stream>>>(W1, W1T, 512, 2048);
  transpose_cvt<<<dim3(16, 64), tb, 0, stream>>>(W2, W2T, 2048, 512);

  gemm_bt<<<dim3(192, 4), 256, 0, stream>>>(srcb, WqT, bq, qb, 24576, 512, 512, 0);
  gemm_bt<<<dim3(192, 4), 256, 0, stream>>>(srcb, WkT, bk, kb, 24576, 512, 512, 0);
  gemm_bt<<<dim3(192, 4), 256, 0, stream>>>(srcb, WvT, bv, vb, 24576, 512, 512, 0);

  attn_fused<<<2048, 384, 0, stream>>>(qb, kb, vb, mat, scout, ctx);

  gemm_bt<<<dim3(192, 4), 256, 0, stream>>>(ctx, WoT, bo, tmp, 24576, 512, 512, 0);
  ln_res<float, __hip_bfloat16><<<24576, 256, 0, stream>>>(tmp, src, g1, be1, xb);
  gemm_bt<<<dim3(192, 16), 256, 0, stream>>>(xb, W1T, b1, hb, 24576, 2048, 512, 1);
  gemm_bt<<<dim3(192, 4), 256, 0, stream>>>(hb, W2T, b2, tmp, 24576, 512, 2048, 0);
  ln_res<__hip_bfloat16, float><<<24576, 256, 0, stream>>>(tmp, xb, g2, be2, yout);
}

// Round 3
// 743.445 us; speedup vs baseline: 1.0388x; 1.0388x over previous
//
#include <hip/hip_runtime.h>
#include <hip/hip_bf16.h>
#include <math.h>

typedef __attribute__((ext_vector_type(8))) short short8;
typedef __attribute__((ext_vector_type(4))) float floatx4;

// ---------------------------------------------------------------- helpers
__device__ __forceinline__ void load_lds16(const void* g, void* l) {
  __builtin_amdgcn_global_load_lds(
      (__attribute__((address_space(1))) void*)(g),
      (__attribute__((address_space(3))) void*)(l), 16, 0, 0);
}

#define MFMA16x16x32(a, b, c) __builtin_amdgcn_mfma_f32_16x16x32_bf16((a), (b), (c), 0, 0, 0)

__device__ __forceinline__ float to_f(float x) { return x; }
__device__ __forceinline__ float to_f(__hip_bfloat16 x) { return __bfloat162float(x); }
__device__ __forceinline__ void st_val(float* p, float v) { *p = v; }
__device__ __forceinline__ void st_val(__hip_bfloat16* p, float v) { *p = __float2bfloat16(v); }

// ---------------------------------------------------------------- fp32 -> bf16 elementwise (src)
__global__ __launch_bounds__(256) void cvt_f32_bf16(const float4* __restrict__ in,
                                                    ushort* __restrict__ out) {
  int i = blockIdx.x * 256 + threadIdx.x;
  float4 v = in[i];
  ushort4 o;
  __hip_bfloat16 b0 = __float2bfloat16(v.x);
  __hip_bfloat16 b1 = __float2bfloat16(v.y);
  __hip_bfloat16 b2 = __float2bfloat16(v.z);
  __hip_bfloat16 b3 = __float2bfloat16(v.w);
  o.x = *(ushort*)&b0; o.y = *(ushort*)&b1; o.z = *(ushort*)&b2; o.w = *(ushort*)&b3;
  *(ushort4*)(out + 4 * i) = o;
}

// ---------------------------------------------------------------- concat 3 bias vectors (512 each)
__global__ void concat3(const float* __restrict__ a, const float* __restrict__ b,
                        const float* __restrict__ c, float* __restrict__ o) {
  int i = blockIdx.x * 256 + threadIdx.x;  // 0..1535
  o[i] = i < 512 ? a[i] : (i < 1024 ? b[i - 512] : c[i - 1024]);
}

// ---------------------------------------------------------------- fp32 weights -> bf16 transposed
__global__ void transpose_cvt(const float* __restrict__ in,
                              __hip_bfloat16* __restrict__ out, int R, int C) {
  __shared__ __hip_bfloat16 tile[32][33];
  int bx = blockIdx.x * 32, by = blockIdx.y * 32;
  int tx = threadIdx.x, ty = threadIdx.y;  // (32,8)
  for (int i = ty; i < 32; i += 8)
    tile[i][tx] = __float2bfloat16(in[(size_t)(by + i) * C + bx + tx]);
  __syncthreads();
  for (int i = ty; i < 32; i += 8) out[(size_t)(bx + i) * R + by + tx] = tile[tx][i];
}

// ---------------------------------------------------------------- GEMM: C[M,N] = A[M,K] @ BT[N,K]^T + bias, opt GELU
// 128x128 tile, BK=64, 4 waves, each wave 64x64 (4x4 MFMA 16x16x32, 2 k-steps).
// grid = (N/128, M/128): consecutive blocks share the A row-tile (L2-hot).
// LDS k-slab layout: element (row,kk) at flat = (kk>>3)*1024 + row*8 + (kk&7)
__global__ __launch_bounds__(256) void gemm_bt(
    const __hip_bfloat16* __restrict__ A,
    const __hip_bfloat16* __restrict__ BT,
    const float* __restrict__ bias,
    __hip_bfloat16* __restrict__ C,
    int M, int N, int K, int act) {
  __shared__ __align__(16) __hip_bfloat16 As[128 * 64];
  __shared__ __align__(16) __hip_bfloat16 Bs[128 * 64];
  const int tid = threadIdx.x;
  const int wave = tid >> 6, lane = tid & 63;
  const int quad = lane >> 4, m = lane & 15;
  const int row0 = blockIdx.y * 128, col0 = blockIdx.x * 128;
  const int wm = (wave >> 1) * 64, wn = (wave & 1) * 64;
  const __hip_bfloat16* Ab = A + (size_t)row0 * K;
  const __hip_bfloat16* Bb = BT + (size_t)col0 * K;

  floatx4 acc[4][4] = {};

  for (int k0 = 0; k0 < K; k0 += 64) {
#pragma unroll
    for (int r = 0; r < 4; ++r) {
      int c = r * 4 + wave;                 // 0..15
      int rowg = ((c & 1) * 64) + lane;
      int kg = k0 + ((c >> 1) * 8);
      load_lds16(Ab + (size_t)rowg * K + kg, &As[c * 512]);
      load_lds16(Bb + (size_t)rowg * K + kg, &Bs[c * 512]);
    }
    __syncthreads();
#pragma unroll
    for (int kk = 0; kk < 2; ++kk) {
      short8 af[4], bfr[4];
#pragma unroll
      for (int i = 0; i < 4; ++i)
        af[i] = *(const short8*)&As[(kk * 4 + quad) * 1024 + (wm + i * 16 + m) * 8];
#pragma unroll
      for (int j = 0; j < 4; ++j)
        bfr[j] = *(const short8*)&Bs[(kk * 4 + quad) * 1024 + (wn + j * 16 + m) * 8];
#pragma unroll
      for (int i = 0; i < 4; ++i)
#pragma unroll
        for (int j = 0; j < 4; ++j)
          acc[i][j] = MFMA16x16x32(af[i], bfr[j], acc[i][j]);
    }
    __syncthreads();
  }

#pragma unroll
  for (int j = 0; j < 4; ++j) {
    int col = col0 + wn + j * 16 + m;
    float bj = bias[col];
#pragma unroll
    for (int i = 0; i < 4; ++i) {
      int rowb = row0 + wm + i * 16 + quad * 4;
#pragma unroll
      for (int r = 0; r < 4; ++r) {
        float v = acc[i][j][r] + bj;
        if (act == 1) {
          // tanh-form GELU (overflow-safe)
          float t = 0.7978845608f * (v + 0.044715f * v * v * v);
          float e2 = __expf(-2.0f * fabsf(t));
          float th = (1.0f - e2) / (1.0f + e2);
          th = t < 0.0f ? -th : th;
          v = 0.5f * v * (1.0f + th);
        }
        C[(size_t)(rowb + r) * N + col] = __float2bfloat16(v);
      }
    }
  }
}

// ---------------------------------------------------------------- fused attention per (b,h)
// qkv fused: row stride 1536; q at col h*64, k at 512+h*64, v at 1024+h*64.
__global__ __launch_bounds__(384) void attn_fused(
    const __hip_bfloat16* __restrict__ qkv,
    const float* __restrict__ mat,
    float* __restrict__ scores,
    __hip_bfloat16* __restrict__ ctx) {
  __shared__ __align__(16) __hip_bfloat16 Ks[96 * 72];   // [l_k][d], pad 64->72
  __shared__ __align__(16) __hip_bfloat16 Vt[64 * 104];  // [d][l_k], pad 96->104
  __shared__ __align__(16) __hip_bfloat16 Ps[96 * 104];  // [l_q][l_k], pad 96->104
  const int bh = blockIdx.x;
  const int b = bh >> 3, h = bh & 7;
  const __hip_bfloat16* qb = qkv + (size_t)b * 96 * 1536 + h * 64;
  const __hip_bfloat16* kb = qb + 512;
  const __hip_bfloat16* vb = qb + 1024;
  const int tid = threadIdx.x;

  // stage K [96][64] -> Ks, 16B chunks
  for (int c = tid; c < 768; c += 384) {
    int row = c >> 3, c8 = (c & 7) * 8;
    *(short8*)&Ks[row * 72 + c8] = *(const short8*)(kb + (size_t)row * 1536 + c8);
  }
  // stage V transposed
  {
    int d = tid & 63;
    for (int l = tid >> 6; l < 96; l += 6) Vt[d * 104 + l] = vb[(size_t)l * 1536 + d];
  }
  __syncthreads();

  const int wave = tid >> 6, lane = tid & 63;
  const int quad = lane >> 4, m = lane & 15;

  // phase 1: S = Q K^T (16 rows per wave, N=96, K=64)
  short8 a0 = *(const short8*)(qb + (size_t)(wave * 16 + m) * 1536 + quad * 8);
  short8 a1 = *(const short8*)(qb + (size_t)(wave * 16 + m) * 1536 + 32 + quad * 8);
  floatx4 s[6];
  const size_t mbase = ((size_t)bh * 96 + wave * 16 + quad * 4) * 96 + m;
#pragma unroll
  for (int ct = 0; ct < 6; ++ct) {
    short8 b0 = *(const short8*)&Ks[(ct * 16 + m) * 72 + quad * 8];
    short8 b1 = *(const short8*)&Ks[(ct * 16 + m) * 72 + 32 + quad * 8];
    floatx4 accv = {};
    accv = MFMA16x16x32(a0, b0, accv);
    accv = MFMA16x16x32(a1, b1, accv);
#pragma unroll
    for (int r = 0; r < 4; ++r) {
      float sv = accv[r] * 0.125f * mat[mbase + (size_t)r * 96 + ct * 16];
      accv[r] = sv;
      scores[mbase + (size_t)r * 96 + ct * 16] = sv;
    }
    s[ct] = accv;
  }

  // softmax over each row
#pragma unroll
  for (int r = 0; r < 4; ++r) {
    float mx = s[0][r];
#pragma unroll
    for (int ct = 1; ct < 6; ++ct) mx = fmaxf(mx, s[ct][r]);
#pragma unroll
    for (int dd = 1; dd < 16; dd <<= 1) mx = fmaxf(mx, __shfl_xor(mx, dd, 64));
    float sum = 0.f;
#pragma unroll
    for (int ct = 0; ct < 6; ++ct) {
      float e = __expf(s[ct][r] - mx);
      s[ct][r] = e;
      sum += e;
    }
#pragma unroll
    for (int dd = 1; dd < 16; dd <<= 1) sum += __shfl_xor(sum, dd, 64);
    float inv = 1.0f / sum;
#pragma unroll
    for (int ct = 0; ct < 6; ++ct)
      Ps[(wave * 16 + quad * 4 + r) * 104 + ct * 16 + m] = __float2bfloat16(s[ct][r] * inv);
  }
  __syncthreads();

  // phase 2: O = P V  (K = 96, 3 k-steps of 32)
  floatx4 o[4] = {};
#pragma unroll
  for (int ks = 0; ks < 3; ++ks) {
    short8 pa = *(const short8*)&Ps[(wave * 16 + m) * 104 + ks * 32 + quad * 8];
#pragma unroll
    for (int ct = 0; ct < 4; ++ct) {
      short8 vv = *(const short8*)&Vt[(ct * 16 + m) * 104 + ks * 32 + quad * 8];
      o[ct] = MFMA16x16x32(pa, vv, o[ct]);
    }
  }
  __hip_bfloat16* cb = ctx + (size_t)b * 96 * 512 + h * 64;
#pragma unroll
  for (int ct = 0; ct < 4; ++ct)
#pragma unroll
    for (int r = 0; r < 4; ++r)
      cb[(size_t)(wave * 16 + quad * 4 + r) * 512 + ct * 16 + m] = __float2bfloat16(o[ct][r]);
}

// ---------------------------------------------------------------- residual + LayerNorm, one block per row (D=512)
template <typename RT, typename OT>
__global__ __launch_bounds__(256) void ln_res(
    const __hip_bfloat16* __restrict__ a, const RT* __restrict__ rsd,
    const float* __restrict__ g, const float* __restrict__ be,
    OT* __restrict__ out) {
  const int row = blockIdx.x;
  const int tid = threadIdx.x;
  const size_t base = (size_t)row * 512 + tid * 2;
  float x0 = __bfloat162float(a[base]) + to_f(rsd[base]);
  float x1 = __bfloat162float(a[base + 1]) + to_f(rsd[base + 1]);
  float s = x0 + x1, s2 = x0 * x0 + x1 * x1;
#pragma unroll
  for (int d = 1; d < 64; d <<= 1) {
    s += __shfl_xor(s, d, 64);
    s2 += __shfl_xor(s2, d, 64);
  }
  __shared__ float red[8];
  const int wave = tid >> 6, lane = tid & 63;
  if (lane == 0) {
    red[wave] = s;
    red[4 + wave] = s2;
  }
  __syncthreads();
  s = red[0] + red[1] + red[2] + red[3];
  s2 = red[4] + red[5] + red[6] + red[7];
  const float mean = s * (1.0f / 512.0f);
  const float var = s2 * (1.0f / 512.0f) - mean * mean;
  const float rstd = rsqrtf(var + 1e-5f);
  st_val(out + base, (x0 - mean) * rstd * g[tid * 2] + be[tid * 2]);
  st_val(out + base + 1, (x1 - mean) * rstd * g[tid * 2 + 1] + be[tid * 2 + 1]);
}

// ---------------------------------------------------------------- launch
extern "C" void kernel_launch(void* const* d_in, const int* in_sizes, int n_in,
                              void* d_out, int out_size, void* d_ws, size_t ws_size,
                              hipStream_t stream) {
  (void)in_sizes; (void)n_in; (void)out_size; (void)ws_size;
  typedef const float* cf;
  typedef __hip_bfloat16* bf;
  cf src = (cf)d_in[0];
  cf Wq = (cf)d_in[1];  cf bq = (cf)d_in[2];
  cf Wk = (cf)d_in[3];  cf bk = (cf)d_in[4];
  cf Wv = (cf)d_in[5];  cf bv = (cf)d_in[6];
  cf mat = (cf)d_in[7];
  cf Wo = (cf)d_in[8];  cf bo = (cf)d_in[9];
  cf g1 = (cf)d_in[10]; cf be1 = (cf)d_in[11];
  cf W1 = (cf)d_in[12]; cf b1 = (cf)d_in[13];
  cf W2 = (cf)d_in[14]; cf b2 = (cf)d_in[15];
  cf g2 = (cf)d_in[16]; cf be2 = (cf)d_in[17];

  char* ws = (char*)d_ws;
  const size_t SZ = (size_t)24576 * 512 * 2;  // 25,165,824 B
  bf qkv = (bf)(ws);                  // [24576][1536] bf16 = 3*SZ
  bf ctx = (bf)(ws + 3 * SZ);
  bf hb  = (bf)(ws);                  // FFN hidden [24576][2048] = 4*SZ; qkv+ctx dead by then
  bf srcb = (bf)(ws + 4 * SZ);        // dead after qkv-gemm
  bf tmp = (bf)(ws + 4 * SZ);         // wo out -> ln1; later ffn2 out -> ln2
  bf xb  = (bf)(ws + 5 * SZ);         // post-LN1 x
  char* wt = ws + 6 * SZ;
  bf WqkvT = (bf)(wt);                          // [1536][512] bf16
  bf WoT = (bf)(wt + 1572864);
  bf W1T = (bf)(wt + 1572864 + 524288);         // [2048][512]
  bf W2T = (bf)(wt + 1572864 + 524288 + 2097152);  // [512][2048]
  float* bqkv = (float*)(wt + 1572864 + 524288 + 2097152 + 2097152);

  float* yout = (float*)d_out;
  float* scout = (float*)d_out + 12582912;  // scores after y

  cvt_f32_bf16<<<12288, 256, 0, stream>>>((const float4*)src, (ushort*)srcb);
  concat3<<<6, 256, 0, stream>>>(bq, bk, bv, bqkv);

  dim3 tb(32, 8);
  transpose_cvt<<<dim3(16, 16), tb, 0, stream>>>(Wq, WqkvT, 512, 512);
  transpose_cvt<<<dim3(16, 16), tb, 0, stream>>>(Wk, WqkvT + 512 * 512, 512, 512);
  transpose_cvt<<<dim3(16, 16), tb, 0, stream>>>(Wv, WqkvT + 1024 * 512, 512, 512);
  transpose_cvt<<<dim3(16, 16), tb, 0, stream>>>(Wo, WoT, 512, 512);
  transpose_cvt<<<dim3(64, 16), tb, 0, stream>>>(W1, W1T, 512, 2048);
  transpose_cvt<<<dim3(16, 64), tb, 0, stream>>>(W2, W2T, 2048, 512);

  gemm_bt<<<dim3(12, 192), 256, 0, stream>>>(srcb, WqkvT, bqkv, qkv, 24576, 1536, 512, 0);

  attn_fused<<<2048, 384, 0, stream>>>(qkv, mat, scout, ctx);

  gemm_bt<<<dim3(4, 192), 256, 0, stream>>>(ctx, WoT, bo, tmp, 24576, 512, 512, 0);
  ln_res<float, __hip_bfloat16><<<24576, 256, 0, stream>>>(tmp, src, g1, be1, xb);
  gemm_bt<<<dim3(16, 192), 256, 0, stream>>>(xb, W1T, b1, hb, 24576, 2048, 512, 1);
  gemm_bt<<<dim3(4, 192), 256, 0, stream>>>(hb, W2T, b2, tmp, 24576, 512, 2048, 0);
  ln_res<__hip_bfloat16, float><<<24576, 256, 0, stream>>>(tmp, xb, g2, be2, yout);
}

// Round 4
// 717.427 us; speedup vs baseline: 1.0765x; 1.0363x over previous
//
#include <hip/hip_runtime.h>
#include <hip/hip_bf16.h>
#include <math.h>

typedef __attribute__((ext_vector_type(8))) short short8;
typedef __attribute__((ext_vector_type(4))) float floatx4;

// ---------------------------------------------------------------- helpers
__device__ __forceinline__ void load_lds16(const void* g, void* l) {
  __builtin_amdgcn_global_load_lds(
      (__attribute__((address_space(1))) void*)(g),
      (__attribute__((address_space(3))) void*)(l), 16, 0, 0);
}

#define MFMA16x16x32(a, b, c) __builtin_amdgcn_mfma_f32_16x16x32_bf16((a), (b), (c), 0, 0, 0)

__device__ __forceinline__ float to_f(float x) { return x; }
__device__ __forceinline__ float to_f(__hip_bfloat16 x) { return __bfloat162float(x); }
__device__ __forceinline__ void st_val(float* p, float v) { *p = v; }
__device__ __forceinline__ void st_val(__hip_bfloat16* p, float v) { *p = __float2bfloat16(v); }

// ---------------------------------------------------------------- fp32 -> bf16 elementwise (src)
__global__ __launch_bounds__(256) void cvt_f32_bf16(const float4* __restrict__ in,
                                                    ushort* __restrict__ out) {
  int i = blockIdx.x * 256 + threadIdx.x;
  float4 v = in[i];
  ushort4 o;
  __hip_bfloat16 b0 = __float2bfloat16(v.x);
  __hip_bfloat16 b1 = __float2bfloat16(v.y);
  __hip_bfloat16 b2 = __float2bfloat16(v.z);
  __hip_bfloat16 b3 = __float2bfloat16(v.w);
  o.x = *(ushort*)&b0; o.y = *(ushort*)&b1; o.z = *(ushort*)&b2; o.w = *(ushort*)&b3;
  *(ushort4*)(out + 4 * i) = o;
}

// ---------------------------------------------------------------- concat 3 bias vectors (512 each)
__global__ void concat3(const float* __restrict__ a, const float* __restrict__ b,
                        const float* __restrict__ c, float* __restrict__ o) {
  int i = blockIdx.x * 256 + threadIdx.x;  // 0..1535
  o[i] = i < 512 ? a[i] : (i < 1024 ? b[i - 512] : c[i - 1024]);
}

// ---------------------------------------------------------------- fp32 weights -> bf16 transposed
__global__ void transpose_cvt(const float* __restrict__ in,
                              __hip_bfloat16* __restrict__ out, int R, int C) {
  __shared__ __hip_bfloat16 tile[32][33];
  int bx = blockIdx.x * 32, by = blockIdx.y * 32;
  int tx = threadIdx.x, ty = threadIdx.y;  // (32,8)
  for (int i = ty; i < 32; i += 8)
    tile[i][tx] = __float2bfloat16(in[(size_t)(by + i) * C + bx + tx]);
  __syncthreads();
  for (int i = ty; i < 32; i += 8) out[(size_t)(bx + i) * R + by + tx] = tile[tx][i];
}

// ---------------------------------------------------------------- GEMM: C[M,N] = A[M,K] @ BT[N,K]^T + bias, opt GELU
// 128x128 tile, BK=64, 4 waves/block. 1-D grid with XCD-aware swizzle:
// all col-tiles of one A row-tile land on the SAME XCD (blockIdx%8 ==
// XCD round-robin heuristic), so A row-tile + whole weight stay L2-hot.
// Requires tiles_y (M/128) divisible by 8.
__global__ __launch_bounds__(256) void gemm_bt(
    const __hip_bfloat16* __restrict__ A,
    const __hip_bfloat16* __restrict__ BT,
    const float* __restrict__ bias,
    __hip_bfloat16* __restrict__ C,
    int M, int N, int K, int act, int tiles_x) {
  __shared__ __align__(16) __hip_bfloat16 As[128 * 64];
  __shared__ __align__(16) __hip_bfloat16 Bs[128 * 64];
  const int tid = threadIdx.x;
  const int wave = tid >> 6, lane = tid & 63;
  const int quad = lane >> 4, m = lane & 15;
  const int L = blockIdx.x;
  const int xcd = L & 7;
  const int j = L >> 3;
  const int row0 = ((j / tiles_x) * 8 + xcd) * 128;
  const int col0 = (j % tiles_x) * 128;
  const int wm = (wave >> 1) * 64, wn = (wave & 1) * 64;
  const __hip_bfloat16* Ab = A + (size_t)row0 * K;
  const __hip_bfloat16* Bb = BT + (size_t)col0 * K;

  floatx4 acc[4][4] = {};

  for (int k0 = 0; k0 < K; k0 += 64) {
#pragma unroll
    for (int r = 0; r < 4; ++r) {
      int c = r * 4 + wave;                 // 0..15
      int rowg = ((c & 1) * 64) + lane;
      int kg = k0 + ((c >> 1) * 8);
      load_lds16(Ab + (size_t)rowg * K + kg, &As[c * 512]);
      load_lds16(Bb + (size_t)rowg * K + kg, &Bs[c * 512]);
    }
    __syncthreads();
#pragma unroll
    for (int kk = 0; kk < 2; ++kk) {
      short8 af[4], bfr[4];
#pragma unroll
      for (int i = 0; i < 4; ++i)
        af[i] = *(const short8*)&As[(kk * 4 + quad) * 1024 + (wm + i * 16 + m) * 8];
#pragma unroll
      for (int j2 = 0; j2 < 4; ++j2)
        bfr[j2] = *(const short8*)&Bs[(kk * 4 + quad) * 1024 + (wn + j2 * 16 + m) * 8];
#pragma unroll
      for (int i = 0; i < 4; ++i)
#pragma unroll
        for (int j2 = 0; j2 < 4; ++j2)
          acc[i][j2] = MFMA16x16x32(af[i], bfr[j2], acc[i][j2]);
    }
    __syncthreads();
  }

#pragma unroll
  for (int j2 = 0; j2 < 4; ++j2) {
    int col = col0 + wn + j2 * 16 + m;
    float bj = bias[col];
#pragma unroll
    for (int i = 0; i < 4; ++i) {
      int rowb = row0 + wm + i * 16 + quad * 4;
#pragma unroll
      for (int r = 0; r < 4; ++r) {
        float v = acc[i][j2][r] + bj;
        if (act == 1) {
          // tanh-form GELU (overflow-safe)
          float t = 0.7978845608f * (v + 0.044715f * v * v * v);
          float e2 = __expf(-2.0f * fabsf(t));
          float th = (1.0f - e2) / (1.0f + e2);
          th = t < 0.0f ? -th : th;
          v = 0.5f * v * (1.0f + th);
        }
        C[(size_t)(rowb + r) * N + col] = __float2bfloat16(v);
      }
    }
  }
}

// ---------------------------------------------------------------- fused attention per (b,h)
// qkv fused: row stride 1536; q at col h*64, k at 512+h*64, v at 1024+h*64.
__global__ __launch_bounds__(384) void attn_fused(
    const __hip_bfloat16* __restrict__ qkv,
    const float* __restrict__ mat,
    float* __restrict__ scores,
    __hip_bfloat16* __restrict__ ctx) {
  __shared__ __align__(16) __hip_bfloat16 Ks[96 * 72];   // [l_k][d], pad 64->72
  __shared__ __align__(16) __hip_bfloat16 Vt[64 * 104];  // [d][l_k], pad 96->104
  __shared__ __align__(16) __hip_bfloat16 Ps[96 * 104];  // [l_q][l_k], pad 96->104
  const int bh = blockIdx.x;
  const int b = bh >> 3, h = bh & 7;
  const __hip_bfloat16* qb = qkv + (size_t)b * 96 * 1536 + h * 64;
  const __hip_bfloat16* kb = qb + 512;
  const __hip_bfloat16* vb = qb + 1024;
  const int tid = threadIdx.x;

  // stage K [96][64] -> Ks, 16B chunks
  for (int c = tid; c < 768; c += 384) {
    int row = c >> 3, c8 = (c & 7) * 8;
    *(short8*)&Ks[row * 72 + c8] = *(const short8*)(kb + (size_t)row * 1536 + c8);
  }
  // stage V transposed
  {
    int d = tid & 63;
    for (int l = tid >> 6; l < 96; l += 6) Vt[d * 104 + l] = vb[(size_t)l * 1536 + d];
  }
  __syncthreads();

  const int wave = tid >> 6, lane = tid & 63;
  const int quad = lane >> 4, m = lane & 15;

  // phase 1: S = Q K^T (16 rows per wave, N=96, K=64)
  short8 a0 = *(const short8*)(qb + (size_t)(wave * 16 + m) * 1536 + quad * 8);
  short8 a1 = *(const short8*)(qb + (size_t)(wave * 16 + m) * 1536 + 32 + quad * 8);
  floatx4 s[6];
  const size_t mbase = ((size_t)bh * 96 + wave * 16 + quad * 4) * 96 + m;
#pragma unroll
  for (int ct = 0; ct < 6; ++ct) {
    short8 b0 = *(const short8*)&Ks[(ct * 16 + m) * 72 + quad * 8];
    short8 b1 = *(const short8*)&Ks[(ct * 16 + m) * 72 + 32 + quad * 8];
    floatx4 accv = {};
    accv = MFMA16x16x32(a0, b0, accv);
    accv = MFMA16x16x32(a1, b1, accv);
#pragma unroll
    for (int r = 0; r < 4; ++r) {
      float sv = accv[r] * 0.125f * mat[mbase + (size_t)r * 96 + ct * 16];
      accv[r] = sv;
      scores[mbase + (size_t)r * 96 + ct * 16] = sv;
    }
    s[ct] = accv;
  }

  // softmax over each row
#pragma unroll
  for (int r = 0; r < 4; ++r) {
    float mx = s[0][r];
#pragma unroll
    for (int ct = 1; ct < 6; ++ct) mx = fmaxf(mx, s[ct][r]);
#pragma unroll
    for (int dd = 1; dd < 16; dd <<= 1) mx = fmaxf(mx, __shfl_xor(mx, dd, 64));
    float sum = 0.f;
#pragma unroll
    for (int ct = 0; ct < 6; ++ct) {
      float e = __expf(s[ct][r] - mx);
      s[ct][r] = e;
      sum += e;
    }
#pragma unroll
    for (int dd = 1; dd < 16; dd <<= 1) sum += __shfl_xor(sum, dd, 64);
    float inv = 1.0f / sum;
#pragma unroll
    for (int ct = 0; ct < 6; ++ct)
      Ps[(wave * 16 + quad * 4 + r) * 104 + ct * 16 + m] = __float2bfloat16(s[ct][r] * inv);
  }
  __syncthreads();

  // phase 2: O = P V  (K = 96, 3 k-steps of 32)
  floatx4 o[4] = {};
#pragma unroll
  for (int ks = 0; ks < 3; ++ks) {
    short8 pa = *(const short8*)&Ps[(wave * 16 + m) * 104 + ks * 32 + quad * 8];
#pragma unroll
    for (int ct = 0; ct < 4; ++ct) {
      short8 vv = *(const short8*)&Vt[(ct * 16 + m) * 104 + ks * 32 + quad * 8];
      o[ct] = MFMA16x16x32(pa, vv, o[ct]);
    }
  }
  __hip_bfloat16* cb = ctx + (size_t)b * 96 * 512 + h * 64;
#pragma unroll
  for (int ct = 0; ct < 4; ++ct)
#pragma unroll
    for (int r = 0; r < 4; ++r)
      cb[(size_t)(wave * 16 + quad * 4 + r) * 512 + ct * 16 + m] = __float2bfloat16(o[ct][r]);
}

// ---------------------------------------------------------------- residual + LayerNorm, one block per row (D=512)
template <typename RT, typename OT>
__global__ __launch_bounds__(256) void ln_res(
    const __hip_bfloat16* __restrict__ a, const RT* __restrict__ rsd,
    const float* __restrict__ g, const float* __restrict__ be,
    OT* __restrict__ out) {
  const int row = blockIdx.x;
  const int tid = threadIdx.x;
  const size_t base = (size_t)row * 512 + tid * 2;
  float x0 = __bfloat162float(a[base]) + to_f(rsd[base]);
  float x1 = __bfloat162float(a[base + 1]) + to_f(rsd[base + 1]);
  float s = x0 + x1, s2 = x0 * x0 + x1 * x1;
#pragma unroll
  for (int d = 1; d < 64; d <<= 1) {
    s += __shfl_xor(s, d, 64);
    s2 += __shfl_xor(s2, d, 64);
  }
  __shared__ float red[8];
  const int wave = tid >> 6, lane = tid & 63;
  if (lane == 0) {
    red[wave] = s;
    red[4 + wave] = s2;
  }
  __syncthreads();
  s = red[0] + red[1] + red[2] + red[3];
  s2 = red[4] + red[5] + red[6] + red[7];
  const float mean = s * (1.0f / 512.0f);
  const float var = s2 * (1.0f / 512.0f) - mean * mean;
  const float rstd = rsqrtf(var + 1e-5f);
  st_val(out + base, (x0 - mean) * rstd * g[tid * 2] + be[tid * 2]);
  st_val(out + base + 1, (x1 - mean) * rstd * g[tid * 2 + 1] + be[tid * 2 + 1]);
}

// ---------------------------------------------------------------- launch
extern "C" void kernel_launch(void* const* d_in, const int* in_sizes, int n_in,
                              void* d_out, int out_size, void* d_ws, size_t ws_size,
                              hipStream_t stream) {
  (void)in_sizes; (void)n_in; (void)out_size; (void)ws_size;
  typedef const float* cf;
  typedef __hip_bfloat16* bf;
  cf src = (cf)d_in[0];
  cf Wq = (cf)d_in[1];  cf bq = (cf)d_in[2];
  cf Wk = (cf)d_in[3];  cf bk = (cf)d_in[4];
  cf Wv = (cf)d_in[5];  cf bv = (cf)d_in[6];
  cf mat = (cf)d_in[7];
  cf Wo = (cf)d_in[8];  cf bo = (cf)d_in[9];
  cf g1 = (cf)d_in[10]; cf be1 = (cf)d_in[11];
  cf W1 = (cf)d_in[12]; cf b1 = (cf)d_in[13];
  cf W2 = (cf)d_in[14]; cf b2 = (cf)d_in[15];
  cf g2 = (cf)d_in[16]; cf be2 = (cf)d_in[17];

  char* ws = (char*)d_ws;
  const size_t SZ = (size_t)24576 * 512 * 2;  // 25,165,824 B
  bf qkv = (bf)(ws);                  // [24576][1536] bf16 = 3*SZ
  bf ctx = (bf)(ws + 3 * SZ);
  bf hb  = (bf)(ws);                  // FFN hidden [24576][2048] = 4*SZ; qkv+ctx dead by then
  bf srcb = (bf)(ws + 4 * SZ);        // dead after qkv-gemm
  bf tmp = (bf)(ws + 4 * SZ);         // wo out -> ln1; later ffn2 out -> ln2
  bf xb  = (bf)(ws + 5 * SZ);         // post-LN1 x
  char* wt = ws + 6 * SZ;
  bf WqkvT = (bf)(wt);                          // [1536][512] bf16
  bf WoT = (bf)(wt + 1572864);
  bf W1T = (bf)(wt + 1572864 + 524288);         // [2048][512]
  bf W2T = (bf)(wt + 1572864 + 524288 + 2097152);  // [512][2048]
  float* bqkv = (float*)(wt + 1572864 + 524288 + 2097152 + 2097152);

  float* yout = (float*)d_out;
  float* scout = (float*)d_out + 12582912;  // scores after y

  cvt_f32_bf16<<<12288, 256, 0, stream>>>((const float4*)src, (ushort*)srcb);
  concat3<<<6, 256, 0, stream>>>(bq, bk, bv, bqkv);

  dim3 tb(32, 8);
  transpose_cvt<<<dim3(16, 16), tb, 0, stream>>>(Wq, WqkvT, 512, 512);
  transpose_cvt<<<dim3(16, 16), tb, 0, stream>>>(Wk, WqkvT + 512 * 512, 512, 512);
  transpose_cvt<<<dim3(16, 16), tb, 0, stream>>>(Wv, WqkvT + 1024 * 512, 512, 512);
  transpose_cvt<<<dim3(16, 16), tb, 0, stream>>>(Wo, WoT, 512, 512);
  transpose_cvt<<<dim3(64, 16), tb, 0, stream>>>(W1, W1T, 512, 2048);
  transpose_cvt<<<dim3(16, 64), tb, 0, stream>>>(W2, W2T, 2048, 512);

  // grids: 1-D, XCD-swizzled inside the kernel (tiles_y = 192 = 24*8)
  gemm_bt<<<2304, 256, 0, stream>>>(srcb, WqkvT, bqkv, qkv, 24576, 1536, 512, 0, 12);

  attn_fused<<<2048, 384, 0, stream>>>(qkv, mat, scout, ctx);

  gemm_bt<<<768, 256, 0, stream>>>(ctx, WoT, bo, tmp, 24576, 512, 512, 0, 4);
  ln_res<float, __hip_bfloat16><<<24576, 256, 0, stream>>>(tmp, src, g1, be1, xb);
  gemm_bt<<<3072, 256, 0, stream>>>(xb, W1T, b1, hb, 24576, 2048, 512, 1, 16);
  gemm_bt<<<768, 256, 0, stream>>>(hb, W2T, b2, tmp, 24576, 512, 2048, 0, 4);
  ln_res<__hip_bfloat16, float><<<24576, 256, 0, stream>>>(tmp, xb, g2, be2, yout);
}

// Round 5
// 715.101 us; speedup vs baseline: 1.0800x; 1.0033x over previous
//
#include <hip/hip_runtime.h>
#include <hip/hip_bf16.h>
#include <math.h>

typedef __attribute__((ext_vector_type(8))) short short8;
typedef __attribute__((ext_vector_type(4))) float floatx4;

// ---------------------------------------------------------------- helpers
__device__ __forceinline__ void load_lds16(const void* g, void* l) {
  __builtin_amdgcn_global_load_lds(
      (__attribute__((address_space(1))) void*)(g),
      (__attribute__((address_space(3))) void*)(l), 16, 0, 0);
}

#define MFMA16x16x32(a, b, c) __builtin_amdgcn_mfma_f32_16x16x32_bf16((a), (b), (c), 0, 0, 0)

__device__ __forceinline__ float to_f(float x) { return x; }
__device__ __forceinline__ float to_f(__hip_bfloat16 x) { return __bfloat162float(x); }
__device__ __forceinline__ void st_val(float* p, float v) { *p = v; }
__device__ __forceinline__ void st_val(__hip_bfloat16* p, float v) { *p = __float2bfloat16(v); }

// ---------------------------------------------------------------- fp32 -> bf16 elementwise (src)
__global__ __launch_bounds__(256) void cvt_f32_bf16(const float4* __restrict__ in,
                                                    ushort* __restrict__ out) {
  int i = blockIdx.x * 256 + threadIdx.x;
  float4 v = in[i];
  ushort4 o;
  __hip_bfloat16 b0 = __float2bfloat16(v.x);
  __hip_bfloat16 b1 = __float2bfloat16(v.y);
  __hip_bfloat16 b2 = __float2bfloat16(v.z);
  __hip_bfloat16 b3 = __float2bfloat16(v.w);
  o.x = *(ushort*)&b0; o.y = *(ushort*)&b1; o.z = *(ushort*)&b2; o.w = *(ushort*)&b3;
  *(ushort4*)(out + 4 * i) = o;
}

// ---------------------------------------------------------------- concat 3 bias vectors (512 each)
__global__ void concat3(const float* __restrict__ a, const float* __restrict__ b,
                        const float* __restrict__ c, float* __restrict__ o) {
  int i = blockIdx.x * 256 + threadIdx.x;  // 0..1535
  o[i] = i < 512 ? a[i] : (i < 1024 ? b[i - 512] : c[i - 1024]);
}

// ---------------------------------------------------------------- fp32 weights -> bf16 transposed
__global__ void transpose_cvt(const float* __restrict__ in,
                              __hip_bfloat16* __restrict__ out, int R, int C) {
  __shared__ __hip_bfloat16 tile[32][33];
  int bx = blockIdx.x * 32, by = blockIdx.y * 32;
  int tx = threadIdx.x, ty = threadIdx.y;  // (32,8)
  for (int i = ty; i < 32; i += 8)
    tile[i][tx] = __float2bfloat16(in[(size_t)(by + i) * C + bx + tx]);
  __syncthreads();
  for (int i = ty; i < 32; i += 8) out[(size_t)(bx + i) * R + by + tx] = tile[tx][i];
}

// ---------------------------------------------------------------- GEMM: C[M,N] = A[M,K] @ BT[N,K]^T + bias, opt GELU
// 256x128 tile, BK=64, 512 threads (8 waves), each wave 64x64 (4x4 MFMA).
// XCD-aware 1-D swizzle: col-tiles of one A row-tile land on the same XCD.
// Requires tiles_y (M/256) divisible by 8 (96 here).
// LDS k-slab layout: element (row,kk) at slab(kk>>3): slab*ROWS*8 + row*8 + (kk&7)
__global__ __launch_bounds__(512) void gemm_bt(
    const __hip_bfloat16* __restrict__ A,
    const __hip_bfloat16* __restrict__ BT,
    const float* __restrict__ bias,
    __hip_bfloat16* __restrict__ C,
    int M, int N, int K, int act, int tiles_x) {
  __shared__ __align__(16) __hip_bfloat16 As[256 * 64];  // 32 KB
  __shared__ __align__(16) __hip_bfloat16 Bs[128 * 64];  // 16 KB
  const int tid = threadIdx.x;
  const int wave = tid >> 6, lane = tid & 63;
  const int quad = lane >> 4, m = lane & 15;
  const int L = blockIdx.x;
  const int xcd = L & 7;
  const int j = L >> 3;
  const int row0 = ((j / tiles_x) * 8 + xcd) * 256;
  const int col0 = (j % tiles_x) * 128;
  const int wm = (wave >> 1) * 64, wn = (wave & 1) * 64;
  const __hip_bfloat16* Ab = A + (size_t)row0 * K;
  const __hip_bfloat16* Bb = BT + (size_t)col0 * K;

  // staging assignments (manual induction pointers)
  // A: 32 chunks, chunk c: slab=c>>2, rowgrp=c&3; wave stages c = 8r+wave, r=0..3
  // B: 16 chunks, chunk c: slab=c>>1, rowgrp=c&1; wave stages c = 8r+wave, r=0..1
  const __hip_bfloat16* pa[4];
  __hip_bfloat16* da[4];
  const __hip_bfloat16* pb[2];
  __hip_bfloat16* db[2];
#pragma unroll
  for (int r = 0; r < 4; ++r) {
    int c = 8 * r + wave;
    pa[r] = Ab + (size_t)((c & 3) * 64 + lane) * K + ((c >> 2) * 8);
    da[r] = &As[(c >> 2) * 2048 + (c & 3) * 512];
  }
#pragma unroll
  for (int r = 0; r < 2; ++r) {
    int c = 8 * r + wave;
    pb[r] = Bb + (size_t)((c & 1) * 64 + lane) * K + ((c >> 1) * 8);
    db[r] = &Bs[(c >> 1) * 1024 + (c & 1) * 512];
  }

  floatx4 acc[4][4] = {};

  for (int k0 = 0; k0 < K; k0 += 64) {
#pragma unroll
    for (int r = 0; r < 4; ++r) {
      load_lds16(pa[r], da[r]);
      pa[r] += 64;
    }
#pragma unroll
    for (int r = 0; r < 2; ++r) {
      load_lds16(pb[r], db[r]);
      pb[r] += 64;
    }
    __syncthreads();
#pragma unroll
    for (int kk = 0; kk < 2; ++kk) {
      short8 af[4], bfr[4];
#pragma unroll
      for (int i = 0; i < 4; ++i)
        af[i] = *(const short8*)&As[(kk * 4 + quad) * 2048 + (wm + i * 16 + m) * 8];
#pragma unroll
      for (int j2 = 0; j2 < 4; ++j2)
        bfr[j2] = *(const short8*)&Bs[(kk * 4 + quad) * 1024 + (wn + j2 * 16 + m) * 8];
#pragma unroll
      for (int i = 0; i < 4; ++i)
#pragma unroll
        for (int j2 = 0; j2 < 4; ++j2)
          acc[i][j2] = MFMA16x16x32(af[i], bfr[j2], acc[i][j2]);
    }
    __syncthreads();
  }

  const int wmr = (wave >> 1) * 64;  // row offset of this wave within the 256-row tile
#pragma unroll
  for (int j2 = 0; j2 < 4; ++j2) {
    int col = col0 + wn + j2 * 16 + m;
    float bj = bias[col];
#pragma unroll
    for (int i = 0; i < 4; ++i) {
      int rowb = row0 + wmr + i * 16 + quad * 4;
#pragma unroll
      for (int r = 0; r < 4; ++r) {
        float v = acc[i][j2][r] + bj;
        if (act == 1) {
          // tanh-form GELU (overflow-safe)
          float t = 0.7978845608f * (v + 0.044715f * v * v * v);
          float e2 = __expf(-2.0f * fabsf(t));
          float th = (1.0f - e2) / (1.0f + e2);
          th = t < 0.0f ? -th : th;
          v = 0.5f * v * (1.0f + th);
        }
        C[(size_t)(rowb + r) * N + col] = __float2bfloat16(v);
      }
    }
  }
}

// ---------------------------------------------------------------- fused attention per (b,h)
// qkv fused: row stride 1536; q at col h*64, k at 512+h*64, v at 1024+h*64.
__global__ __launch_bounds__(384) void attn_fused(
    const __hip_bfloat16* __restrict__ qkv,
    const float* __restrict__ mat,
    float* __restrict__ scores,
    __hip_bfloat16* __restrict__ ctx) {
  __shared__ __align__(16) __hip_bfloat16 Ks[96 * 72];   // [l_k][d], pad 64->72
  __shared__ __align__(16) __hip_bfloat16 Vt[64 * 104];  // [d][l_k], pad 96->104
  __shared__ __align__(16) __hip_bfloat16 Ps[96 * 104];  // [l_q][l_k], pad 96->104
  const int bh = blockIdx.x;
  const int b = bh >> 3, h = bh & 7;
  const __hip_bfloat16* qb = qkv + (size_t)b * 96 * 1536 + h * 64;
  const __hip_bfloat16* kb = qb + 512;
  const __hip_bfloat16* vb = qb + 1024;
  const int tid = threadIdx.x;

  // stage K [96][64] -> Ks, 16B chunks
  for (int c = tid; c < 768; c += 384) {
    int row = c >> 3, c8 = (c & 7) * 8;
    *(short8*)&Ks[row * 72 + c8] = *(const short8*)(kb + (size_t)row * 1536 + c8);
  }
  // stage V transposed
  {
    int d = tid & 63;
    for (int l = tid >> 6; l < 96; l += 6) Vt[d * 104 + l] = vb[(size_t)l * 1536 + d];
  }
  __syncthreads();

  const int wave = tid >> 6, lane = tid & 63;
  const int quad = lane >> 4, m = lane & 15;

  // phase 1: S = Q K^T (16 rows per wave, N=96, K=64)
  short8 a0 = *(const short8*)(qb + (size_t)(wave * 16 + m) * 1536 + quad * 8);
  short8 a1 = *(const short8*)(qb + (size_t)(wave * 16 + m) * 1536 + 32 + quad * 8);
  floatx4 s[6];
  const size_t mbase = ((size_t)bh * 96 + wave * 16 + quad * 4) * 96 + m;
#pragma unroll
  for (int ct = 0; ct < 6; ++ct) {
    short8 b0 = *(const short8*)&Ks[(ct * 16 + m) * 72 + quad * 8];
    short8 b1 = *(const short8*)&Ks[(ct * 16 + m) * 72 + 32 + quad * 8];
    floatx4 accv = {};
    accv = MFMA16x16x32(a0, b0, accv);
    accv = MFMA16x16x32(a1, b1, accv);
#pragma unroll
    for (int r = 0; r < 4; ++r) {
      float sv = accv[r] * 0.125f * mat[mbase + (size_t)r * 96 + ct * 16];
      accv[r] = sv;
      scores[mbase + (size_t)r * 96 + ct * 16] = sv;
    }
    s[ct] = accv;
  }

  // softmax over each row
#pragma unroll
  for (int r = 0; r < 4; ++r) {
    float mx = s[0][r];
#pragma unroll
    for (int ct = 1; ct < 6; ++ct) mx = fmaxf(mx, s[ct][r]);
#pragma unroll
    for (int dd = 1; dd < 16; dd <<= 1) mx = fmaxf(mx, __shfl_xor(mx, dd, 64));
    float sum = 0.f;
#pragma unroll
    for (int ct = 0; ct < 6; ++ct) {
      float e = __expf(s[ct][r] - mx);
      s[ct][r] = e;
      sum += e;
    }
#pragma unroll
    for (int dd = 1; dd < 16; dd <<= 1) sum += __shfl_xor(sum, dd, 64);
    float inv = 1.0f / sum;
#pragma unroll
    for (int ct = 0; ct < 6; ++ct)
      Ps[(wave * 16 + quad * 4 + r) * 104 + ct * 16 + m] = __float2bfloat16(s[ct][r] * inv);
  }
  __syncthreads();

  // phase 2: O = P V  (K = 96, 3 k-steps of 32)
  floatx4 o[4] = {};
#pragma unroll
  for (int ks = 0; ks < 3; ++ks) {
    short8 pa = *(const short8*)&Ps[(wave * 16 + m) * 104 + ks * 32 + quad * 8];
#pragma unroll
    for (int ct = 0; ct < 4; ++ct) {
      short8 vv = *(const short8*)&Vt[(ct * 16 + m) * 104 + ks * 32 + quad * 8];
      o[ct] = MFMA16x16x32(pa, vv, o[ct]);
    }
  }
  __hip_bfloat16* cb = ctx + (size_t)b * 96 * 512 + h * 64;
#pragma unroll
  for (int ct = 0; ct < 4; ++ct)
#pragma unroll
    for (int r = 0; r < 4; ++r)
      cb[(size_t)(wave * 16 + quad * 4 + r) * 512 + ct * 16 + m] = __float2bfloat16(o[ct][r]);
}

// ---------------------------------------------------------------- residual + LayerNorm, one block per row (D=512)
template <typename RT, typename OT>
__global__ __launch_bounds__(256) void ln_res(
    const __hip_bfloat16* __restrict__ a, const RT* __restrict__ rsd,
    const float* __restrict__ g, const float* __restrict__ be,
    OT* __restrict__ out) {
  const int row = blockIdx.x;
  const int tid = threadIdx.x;
  const size_t base = (size_t)row * 512 + tid * 2;
  float x0 = __bfloat162float(a[base]) + to_f(rsd[base]);
  float x1 = __bfloat162float(a[base + 1]) + to_f(rsd[base + 1]);
  float s = x0 + x1, s2 = x0 * x0 + x1 * x1;
#pragma unroll
  for (int d = 1; d < 64; d <<= 1) {
    s += __shfl_xor(s, d, 64);
    s2 += __shfl_xor(s2, d, 64);
  }
  __shared__ float red[8];
  const int wave = tid >> 6, lane = tid & 63;
  if (lane == 0) {
    red[wave] = s;
    red[4 + wave] = s2;
  }
  __syncthreads();
  s = red[0] + red[1] + red[2] + red[3];
  s2 = red[4] + red[5] + red[6] + red[7];
  const float mean = s * (1.0f / 512.0f);
  const float var = s2 * (1.0f / 512.0f) - mean * mean;
  const float rstd = rsqrtf(var + 1e-5f);
  st_val(out + base, (x0 - mean) * rstd * g[tid * 2] + be[tid * 2]);
  st_val(out + base + 1, (x1 - mean) * rstd * g[tid * 2 + 1] + be[tid * 2 + 1]);
}

// ---------------------------------------------------------------- launch
extern "C" void kernel_launch(void* const* d_in, const int* in_sizes, int n_in,
                              void* d_out, int out_size, void* d_ws, size_t ws_size,
                              hipStream_t stream) {
  (void)in_sizes; (void)n_in; (void)out_size; (void)ws_size;
  typedef const float* cf;
  typedef __hip_bfloat16* bf;
  cf src = (cf)d_in[0];
  cf Wq = (cf)d_in[1];  cf bq = (cf)d_in[2];
  cf Wk = (cf)d_in[3];  cf bk = (cf)d_in[4];
  cf Wv = (cf)d_in[5];  cf bv = (cf)d_in[6];
  cf mat = (cf)d_in[7];
  cf Wo = (cf)d_in[8];  cf bo = (cf)d_in[9];
  cf g1 = (cf)d_in[10]; cf be1 = (cf)d_in[11];
  cf W1 = (cf)d_in[12]; cf b1 = (cf)d_in[13];
  cf W2 = (cf)d_in[14]; cf b2 = (cf)d_in[15];
  cf g2 = (cf)d_in[16]; cf be2 = (cf)d_in[17];

  char* ws = (char*)d_ws;
  const size_t SZ = (size_t)24576 * 512 * 2;  // 25,165,824 B
  bf qkv = (bf)(ws);                  // [24576][1536] bf16 = 3*SZ
  bf ctx = (bf)(ws + 3 * SZ);
  bf hb  = (bf)(ws);                  // FFN hidden [24576][2048] = 4*SZ; qkv+ctx dead by then
  bf srcb = (bf)(ws + 4 * SZ);        // dead after qkv-gemm
  bf tmp = (bf)(ws + 4 * SZ);         // wo out -> ln1; later ffn2 out -> ln2
  bf xb  = (bf)(ws + 5 * SZ);         // post-LN1 x
  char* wt = ws + 6 * SZ;
  bf WqkvT = (bf)(wt);                          // [1536][512] bf16
  bf WoT = (bf)(wt + 1572864);
  bf W1T = (bf)(wt + 1572864 + 524288);         // [2048][512]
  bf W2T = (bf)(wt + 1572864 + 524288 + 2097152);  // [512][2048]
  float* bqkv = (float*)(wt + 1572864 + 524288 + 2097152 + 2097152);

  float* yout = (float*)d_out;
  float* scout = (float*)d_out + 12582912;  // scores after y

  cvt_f32_bf16<<<12288, 256, 0, stream>>>((const float4*)src, (ushort*)srcb);
  concat3<<<6, 256, 0, stream>>>(bq, bk, bv, bqkv);

  dim3 tb(32, 8);
  transpose_cvt<<<dim3(16, 16), tb, 0, stream>>>(Wq, WqkvT, 512, 512);
  transpose_cvt<<<dim3(16, 16), tb, 0, stream>>>(Wk, WqkvT + 512 * 512, 512, 512);
  transpose_cvt<<<dim3(16, 16), tb, 0, stream>>>(Wv, WqkvT + 1024 * 512, 512, 512);
  transpose_cvt<<<dim3(16, 16), tb, 0, stream>>>(Wo, WoT, 512, 512);
  transpose_cvt<<<dim3(64, 16), tb, 0, stream>>>(W1, W1T, 512, 2048);
  transpose_cvt<<<dim3(16, 64), tb, 0, stream>>>(W2, W2T, 2048, 512);

  // grids: 1-D, XCD-swizzled inside the kernel; tiles_y = 24576/256 = 96 = 12*8
  gemm_bt<<<1152, 512, 0, stream>>>(srcb, WqkvT, bqkv, qkv, 24576, 1536, 512, 0, 12);

  attn_fused<<<2048, 384, 0, stream>>>(qkv, mat, scout, ctx);

  gemm_bt<<<384, 512, 0, stream>>>(ctx, WoT, bo, tmp, 24576, 512, 512, 0, 4);
  ln_res<float, __hip_bfloat16><<<24576, 256, 0, stream>>>(tmp, src, g1, be1, xb);
  gemm_bt<<<1536, 512, 0, stream>>>(xb, W1T, b1, hb, 24576, 2048, 512, 1, 16);
  gemm_bt<<<384, 512, 0, stream>>>(hb, W2T, b2, tmp, 24576, 512, 2048, 0, 4);
  ln_res<__hip_bfloat16, float><<<24576, 256, 0, stream>>>(tmp, xb, g2, be2, yout);
}